// Round 1
// baseline (708.144 us; speedup 1.0000x reference)
//
#include <hip/hip_runtime.h>
#include <hip/hip_bf16.h>
#include <stdint.h>

// ---------------------------------------------------------------------------
// GPT-OSS sliding-window attention block, MI355X (gfx950).
// B=1 S=4096 HID=2880 HQ=64 HKV=8 D=64 W=128, sinks, RoPE.
// bf16 MFMA pipeline:
//   cast/transpose -> fused QKV GEMM -> RoPE -> V^T -> banded flash attn
//   -> output GEMM (f32 out).
// GEMM = m97 structure: 128x128 tile, BK=32, global_load_lds(16B), 2 barriers.
// Workspace: ~150 MB.
// ---------------------------------------------------------------------------

typedef __attribute__((ext_vector_type(8))) short bf16x8;
typedef __attribute__((ext_vector_type(4))) float f32x4;
typedef __attribute__((ext_vector_type(8))) unsigned short ushort8;

#define DEVI static __device__ __forceinline__

DEVI unsigned short f2bf(float f) {
  unsigned x = __float_as_uint(f);
  return (unsigned short)((x + 0x7fffu + ((x >> 16) & 1u)) >> 16);  // RNE
}
DEVI float bf2f(unsigned short u) { return __uint_as_float(((unsigned)u) << 16); }

DEVI void async16(const void* g, void* l) {
  __builtin_amdgcn_global_load_lds(
      (const __attribute__((address_space(1))) void*)g,
      (__attribute__((address_space(3))) void*)l, 16, 0, 0);
}

// ---------------- cast f32 -> bf16 (vectorized) ----------------------------
__global__ void k_cast_bf16(const float* __restrict__ src,
                            unsigned short* __restrict__ dst, long n) {
  long i = ((long)blockIdx.x * blockDim.x + threadIdx.x) * 4;
  const long stride = (long)gridDim.x * blockDim.x * 4;
  for (; i < n; i += stride) {
    float4 v = *(const float4*)(src + i);
    ushort4 o = make_ushort4(f2bf(v.x), f2bf(v.y), f2bf(v.z), f2bf(v.w));
    *(ushort4*)(dst + i) = o;
  }
}

// ------------- transpose + cast: src f32 [R][C] -> dst bf16 [*][R] ---------
// dst row n (= src col c0+n) is zero-filled when n >= C (Wo N-padding).
__global__ void k_transpose_cast(const float* __restrict__ src,
                                 unsigned short* __restrict__ dst,
                                 int R, int C) {
  __shared__ float tile[64][65];
  const int t = threadIdx.x;
  const int r0 = blockIdx.y * 64, c0 = blockIdx.x * 64;
#pragma unroll
  for (int i = 0; i < 16; i++) {
    int r = i * 4 + (t >> 6), c = t & 63;
    float v = 0.f;
    if (c0 + c < C) v = src[(long)(r0 + r) * C + c0 + c];
    tile[r][c] = v;
  }
  __syncthreads();
#pragma unroll
  for (int i = 0; i < 16; i++) {
    int nn = i * 4 + (t >> 6), kk = t & 63;
    dst[(long)(c0 + nn) * R + r0 + kk] = f2bf(tile[kk][nn]);
  }
}

// ---------------- concat bias [bq|bk|bv] -> [5120] -------------------------
__global__ void k_concat_bias(const float* __restrict__ bq,
                              const float* __restrict__ bk,
                              const float* __restrict__ bv,
                              float* __restrict__ dst) {
  int i = blockIdx.x * 256 + threadIdx.x;
  if (i < 5120)
    dst[i] = (i < 4096) ? bq[i] : ((i < 4608) ? bk[i - 4096] : bv[i - 4608]);
}

// ---------------- GEMM: C = A[M][K] * Bt[N][K]^T + bias --------------------
// 128x128 tile, BK=32, 4 waves (2x2), 16x16x32 bf16 MFMA, A/B staged with
// global_load_lds dwordx4.  OUT_BF16: bf16 C; NMASK: mask columns >= Nreal.
template <bool OUT_BF16, bool NMASK>
__global__ __launch_bounds__(256) void k_gemm_bt(
    const unsigned short* __restrict__ A, const unsigned short* __restrict__ Bt,
    const float* __restrict__ bias, void* __restrict__ Cout, int M, int K,
    int ldc, int Nreal) {
  __shared__ unsigned short As[128 * 32];
  __shared__ unsigned short Bs[128 * 32];
  const int tid = threadIdx.x;
  const int w = tid >> 6, l = tid & 63;
  const int wm = w >> 1, wn = w & 1;
  const int lg = l >> 4, ll = l & 15;
  const long m0 = (long)blockIdx.x * 128;
  const long n0 = (long)blockIdx.y * 128;

  f32x4 acc[4][4];
#pragma unroll
  for (int i = 0; i < 4; i++)
#pragma unroll
    for (int j = 0; j < 4; j++) acc[i][j] = (f32x4){0.f, 0.f, 0.f, 0.f};

  const unsigned short* ga = A + (m0 + 32 * w + (l >> 2)) * (long)K + (l & 3) * 8;
  const unsigned short* gb = Bt + (n0 + 32 * w + (l >> 2)) * (long)K + (l & 3) * 8;
  unsigned short* lA = As + 32 * w * 32;  // wave-uniform LDS base (bytes: w*2048)
  unsigned short* lB = Bs + 32 * w * 32;

  for (int kt = 0; kt < K; kt += 32) {
    async16(ga + kt, lA);
    async16(ga + kt + 16 * (long)K, lA + 16 * 32);
    async16(gb + kt, lB);
    async16(gb + kt + 16 * (long)K, lB + 16 * 32);
    __syncthreads();
    bf16x8 af[4], bfr[4];
#pragma unroll
    for (int m = 0; m < 4; m++)
      af[m] = *(const bf16x8*)&As[(wm * 64 + m * 16 + ll) * 32 + 8 * lg];
#pragma unroll
    for (int nn = 0; nn < 4; nn++)
      bfr[nn] = *(const bf16x8*)&Bs[(wn * 64 + nn * 16 + ll) * 32 + 8 * lg];
#pragma unroll
    for (int m = 0; m < 4; m++)
#pragma unroll
      for (int nn = 0; nn < 4; nn++)
        acc[m][nn] = __builtin_amdgcn_mfma_f32_16x16x32_bf16(af[m], bfr[nn],
                                                             acc[m][nn], 0, 0, 0);
    __syncthreads();
  }

  // epilogue: C layout col = l&15, row = (l>>4)*4 + j  [m89-verified]
#pragma unroll
  for (int nn = 0; nn < 4; nn++) {
    int col = (int)n0 + wn * 64 + nn * 16 + ll;
    bool ok = (!NMASK) || (col < Nreal);
    float bv_ = ok ? bias[col] : 0.f;
#pragma unroll
    for (int m = 0; m < 4; m++) {
      long row = m0 + wm * 64 + m * 16 + lg * 4;
#pragma unroll
      for (int j = 0; j < 4; j++) {
        float v = acc[m][nn][j] + bv_;
        if (ok) {
          if (OUT_BF16)
            ((unsigned short*)Cout)[(row + j) * (long)ldc + col] = f2bf(v);
          else
            ((float*)Cout)[(row + j) * (long)ldc + col] = v;
        }
      }
    }
  }
}

// ---------------- RoPE in place on qkv[s][0..4607] -------------------------
// q heads 0..63 (cols 0..4095), k heads 64..71 (cols 4096..4607); pairs
// (d, d+32) within each head; cos=fc[s][d], sin=fc[s][32+d].
__global__ void k_rope(unsigned short* __restrict__ qkv,
                       const float* __restrict__ fc) {
  const int s = blockIdx.x;
  const float* f = fc + (long)s * 64;
  unsigned short* row = qkv + (long)s * 5120;
  for (int i = threadIdx.x; i < 72 * 32; i += 256) {
    int hh = i >> 5, d = i & 31;
    float c = f[d], sn = f[32 + d];
    int base = hh * 64 + d;
    float x1 = bf2f(row[base]), x2 = bf2f(row[base + 32]);
    row[base] = f2bf(x1 * c - x2 * sn);
    row[base + 32] = f2bf(x2 * c + x1 * sn);
  }
}

// ---------------- V^T: qkv v-region [s][4608+j] -> vt [j][s] ---------------
__global__ void k_transpose_v(const unsigned short* __restrict__ qkv,
                              unsigned short* __restrict__ vt) {
  __shared__ unsigned short tile[64][72];
  const int t = threadIdx.x;
  const int ts = blockIdx.x;  // 64 S-tiles
  const int tj = blockIdx.y;  // 8 col-tiles
#pragma unroll
  for (int i = 0; i < 2; i++) {
    int s = i * 32 + (t >> 3), j = (t & 7) * 8;
    *(ushort8*)&tile[s][j] =
        *(const ushort8*)(qkv + (long)(ts * 64 + s) * 5120 + 4608 + tj * 64 + j);
  }
  __syncthreads();
  int j = t >> 2, s0 = (t & 3) * 16;
  ushort8 v0, v1;
#pragma unroll
  for (int x = 0; x < 8; x++) {
    v0[x] = tile[s0 + x][j];
    v1[x] = tile[s0 + 8 + x][j];
  }
  unsigned short* dst = vt + (long)(tj * 64 + j) * 4096 + ts * 64 + s0;
  *(ushort8*)dst = v0;
  *(ushort8*)(dst + 8) = v1;
}

// ---------------- banded flash attention with sinks ------------------------
// grid (nb=32, HQ=64); block 256 (4 waves x 32 query rows).
// Keys for q-block n: global [(n-1)*128, (n+1)*128) in 2 chunks of 128.
// Band: key kg valid for query qg iff qg-127 <= kg <= qg.
__global__ __launch_bounds__(256) void k_attn(
    const unsigned short* __restrict__ qkv, const unsigned short* __restrict__ vt,
    const float* __restrict__ sinks, unsigned short* __restrict__ o) {
  __shared__ unsigned short Ps[4][32][136];  // per-wave P, padded (2-way reads)
  __shared__ unsigned short Ks[128][72];     // padded: frag reads 2-way
  __shared__ unsigned short Vts[64][136];    // V^T chunk, padded
  unsigned short(*Qs)[72] = (unsigned short(*)[72]) & Ps[0][0][0];  // alias

  const int n = blockIdx.x, h = blockIdx.y;
  const int kvh = h >> 3;
  const int t = threadIdx.x, w = t >> 6, l = t & 63;
  const int lg = l >> 4, ll = l & 15;

  // stage Q (128 x 64), then hoist Q frags to regs before Ps overwrites Qs
#pragma unroll
  for (int i = 0; i < 4; i++) {
    int s = 32 * i + (t >> 3), c8 = (t & 7) * 8;
    *(ushort8*)&Qs[s][c8] =
        *(const ushort8*)(qkv + (long)(n * 128 + s) * 5120 + h * 64 + c8);
  }
  __syncthreads();
  bf16x8 aq[2][2];
#pragma unroll
  for (int m = 0; m < 2; m++)
#pragma unroll
    for (int ks = 0; ks < 2; ks++)
      aq[m][ks] = *(const bf16x8*)&Qs[32 * w + 16 * m + ll][32 * ks + 8 * lg];

  f32x4 oacc[2][4];
#pragma unroll
  for (int m = 0; m < 2; m++)
#pragma unroll
    for (int nt = 0; nt < 4; nt++) oacc[m][nt] = (f32x4){0.f, 0.f, 0.f, 0.f};
  float mrun[2][4], lrun[2][4];
#pragma unroll
  for (int m = 0; m < 2; m++)
#pragma unroll
    for (int j = 0; j < 4; j++) { mrun[m][j] = -3.0e38f; lrun[m][j] = 0.f; }

  for (int ch = (n == 0 ? 1 : 0); ch < 2; ch++) {
    const int kbase = (n - 1 + ch) * 128;
    // stage K chunk [128 keys][64]
#pragma unroll
    for (int i = 0; i < 4; i++) {
      int c = 32 * i + (t >> 3), c8 = (t & 7) * 8;
      *(ushort8*)&Ks[c][c8] = *(const ushort8*)(
          qkv + (long)(kbase + c) * 5120 + 4096 + kvh * 64 + c8);
    }
    // stage V^T chunk [64 d][128 keys]
#pragma unroll
    for (int i = 0; i < 4; i++) {
      int d = 16 * i + (t >> 4), c8 = (t & 15) * 8;
      *(ushort8*)&Vts[d][c8] =
          *(const ushort8*)(vt + (long)(kvh * 64 + d) * 4096 + kbase + c8);
    }
    __syncthreads();

    // S = Q K^T  (per wave: 32 rows x 128 keys)
    f32x4 sacc[2][8];
#pragma unroll
    for (int m = 0; m < 2; m++)
#pragma unroll
      for (int ct = 0; ct < 8; ct++) sacc[m][ct] = (f32x4){0.f, 0.f, 0.f, 0.f};
#pragma unroll
    for (int ct = 0; ct < 8; ct++)
#pragma unroll
      for (int ks = 0; ks < 2; ks++) {
        bf16x8 bk = *(const bf16x8*)&Ks[16 * ct + ll][32 * ks + 8 * lg];
#pragma unroll
        for (int m = 0; m < 2; m++)
          sacc[m][ct] =
              __builtin_amdgcn_mfma_f32_16x16x32_bf16(aq[m][ks], bk, sacc[m][ct], 0, 0, 0);
      }

    // mask + scale + chunk row-max
    float cmax[2][4];
#pragma unroll
    for (int m = 0; m < 2; m++)
#pragma unroll
      for (int j = 0; j < 4; j++) cmax[m][j] = -3.0e38f;
#pragma unroll
    for (int m = 0; m < 2; m++)
#pragma unroll
      for (int ct = 0; ct < 8; ct++)
#pragma unroll
        for (int j = 0; j < 4; j++) {
          int trow = 32 * w + 16 * m + 4 * lg + j;
          int cc = ch * 128 + 16 * ct + ll;
          bool valid = (cc >= trow + 1) && (cc <= trow + 128);
          float sv = valid ? sacc[m][ct][j] * 0.125f : -1.0e30f;
          sacc[m][ct][j] = sv;
          cmax[m][j] = fmaxf(cmax[m][j], sv);
        }
#pragma unroll
    for (int m = 0; m < 2; m++)
#pragma unroll
      for (int j = 0; j < 4; j++) {
        float v = cmax[m][j];
#pragma unroll
        for (int off = 1; off < 16; off <<= 1) v = fmaxf(v, __shfl_xor(v, off));
        cmax[m][j] = v;
      }

    // online-softmax update
    float fsc[2][4];
#pragma unroll
    for (int m = 0; m < 2; m++)
#pragma unroll
      for (int j = 0; j < 4; j++) {
        float mnew = fmaxf(mrun[m][j], cmax[m][j]);
        fsc[m][j] = __expf(mrun[m][j] - mnew);
        mrun[m][j] = mnew;
        lrun[m][j] *= fsc[m][j];
      }

    // P = exp(S - m), write to per-wave LDS, accumulate row sums
    float psum[2][4];
#pragma unroll
    for (int m = 0; m < 2; m++)
#pragma unroll
      for (int j = 0; j < 4; j++) psum[m][j] = 0.f;
#pragma unroll
    for (int m = 0; m < 2; m++)
#pragma unroll
      for (int ct = 0; ct < 8; ct++)
#pragma unroll
        for (int j = 0; j < 4; j++) {
          float p = __expf(sacc[m][ct][j] - mrun[m][j]);
          psum[m][j] += p;
          Ps[w][16 * m + 4 * lg + j][16 * ct + ll] = f2bf(p);
        }
#pragma unroll
    for (int m = 0; m < 2; m++)
#pragma unroll
      for (int j = 0; j < 4; j++) {
        float v = psum[m][j];
#pragma unroll
        for (int off = 1; off < 16; off <<= 1) v += __shfl_xor(v, off);
        lrun[m][j] += v;
#pragma unroll
        for (int nt = 0; nt < 4; nt++) oacc[m][nt][j] *= fsc[m][j];
      }

    // drain this wave's Ps writes before reading A-frags (wave-local buffer)
    asm volatile("s_waitcnt lgkmcnt(0)" ::: "memory");

    // O += P V  (K = 128 keys, 4 k-steps)
#pragma unroll
    for (int ks = 0; ks < 4; ks++) {
      bf16x8 pa[2], vb[4];
#pragma unroll
      for (int m = 0; m < 2; m++)
        pa[m] = *(const bf16x8*)&Ps[w][16 * m + ll][32 * ks + 8 * lg];
#pragma unroll
      for (int nt = 0; nt < 4; nt++)
        vb[nt] = *(const bf16x8*)&Vts[16 * nt + ll][32 * ks + 8 * lg];
#pragma unroll
      for (int m = 0; m < 2; m++)
#pragma unroll
        for (int nt = 0; nt < 4; nt++)
          oacc[m][nt] =
              __builtin_amdgcn_mfma_f32_16x16x32_bf16(pa[m], vb[nt], oacc[m][nt], 0, 0, 0);
    }
    __syncthreads();  // protect Ks/Vts/Ps before next chunk stages
  }

  // sink + normalize + store
  const float sk = sinks[h];
#pragma unroll
  for (int m = 0; m < 2; m++)
#pragma unroll
    for (int j = 0; j < 4; j++) {
      float mf = fmaxf(mrun[m][j], sk);
      float f = __expf(mrun[m][j] - mf);
      float denom = lrun[m][j] * f + __expf(sk - mf);
      float sc = f / denom;
#pragma unroll
      for (int nt = 0; nt < 4; nt++) oacc[m][nt][j] *= sc;
    }
#pragma unroll
  for (int m = 0; m < 2; m++)
#pragma unroll
    for (int nt = 0; nt < 4; nt++)
#pragma unroll
      for (int j = 0; j < 4; j++) {
        long row = (long)n * 128 + 32 * w + 16 * m + 4 * lg + j;
        int col = h * 64 + 16 * nt + ll;
        o[row * 4096 + col] = f2bf(oacc[m][nt][j]);
      }
}

// ---------------------------------------------------------------------------
extern "C" void kernel_launch(void* const* d_in, const int* in_sizes, int n_in,
                              void* d_out, int out_size, void* d_ws,
                              size_t ws_size, hipStream_t stream) {
  const float* x = (const float*)d_in[0];
  const float* fc = (const float*)d_in[1];
  const float* Wq = (const float*)d_in[2];
  const float* bq = (const float*)d_in[3];
  const float* Wk = (const float*)d_in[4];
  const float* bk = (const float*)d_in[5];
  const float* Wv = (const float*)d_in[6];
  const float* bv = (const float*)d_in[7];
  const float* Wo = (const float*)d_in[8];
  const float* bo = (const float*)d_in[9];
  const float* sinks = (const float*)d_in[10];
  float* out = (float*)d_out;

  char* p = (char*)d_ws;
  unsigned short* xb = (unsigned short*)p;     p += (size_t)4096 * 2880 * 2;
  unsigned short* Wqkvt = (unsigned short*)p;  p += (size_t)5120 * 2880 * 2;
  unsigned short* Wot = (unsigned short*)p;    p += (size_t)2944 * 4096 * 2;
  unsigned short* qkv = (unsigned short*)p;    p += (size_t)4096 * 5120 * 2;
  unsigned short* vt = (unsigned short*)p;     p += (size_t)512 * 4096 * 2;
  unsigned short* obuf = (unsigned short*)p;   p += (size_t)4096 * 4096 * 2;
  float* biasq = (float*)p;                    p += (size_t)5120 * 4;
  // total ~150 MB

  k_cast_bf16<<<2048, 256, 0, stream>>>(x, xb, (long)4096 * 2880);
  k_transpose_cast<<<dim3(64, 45), 256, 0, stream>>>(Wq, Wqkvt, 2880, 4096);
  k_transpose_cast<<<dim3(8, 45), 256, 0, stream>>>(
      Wk, Wqkvt + (size_t)4096 * 2880, 2880, 512);
  k_transpose_cast<<<dim3(8, 45), 256, 0, stream>>>(
      Wv, Wqkvt + (size_t)4608 * 2880, 2880, 512);
  k_transpose_cast<<<dim3(46, 64), 256, 0, stream>>>(Wo, Wot, 4096, 2880);
  k_concat_bias<<<20, 256, 0, stream>>>(bq, bk, bv, biasq);

  // fused QKV GEMM: [4096 x 2880] @ [2880 x 5120] -> qkv bf16
  k_gemm_bt<true, false><<<dim3(32, 40), 256, 0, stream>>>(
      xb, Wqkvt, biasq, qkv, 4096, 2880, 5120, 5120);

  k_rope<<<4096, 256, 0, stream>>>(qkv, fc);
  k_transpose_v<<<dim3(64, 8), 256, 0, stream>>>(qkv, vt);

  k_attn<<<dim3(32, 64), 256, 0, stream>>>(qkv, vt, sinks, obuf);

  // output GEMM: [4096 x 4096] @ [4096 x 2880] -> f32 out (N masked to 2880)
  k_gemm_bt<false, true><<<dim3(32, 23), 256, 0, stream>>>(
      obuf, Wot, bo, out, 4096, 4096, 2880, 2880);
}

// Round 2
// 654.685 us; speedup vs baseline: 1.0817x; 1.0817x over previous
//
#include <hip/hip_runtime.h>
#include <hip/hip_bf16.h>
#include <stdint.h>

// ---------------------------------------------------------------------------
// GPT-OSS sliding-window attention block, MI355X (gfx950).
// B=1 S=4096 HID=2880 HQ=64 HKV=8 D=64 W=128, sinks, RoPE.
// Pipeline: cast/transpose -> fused QKV GEMM (256^2 8-phase) -> RoPE -> V^T
//   -> banded flash attn -> output GEMM (256^2 8-phase, f32 out).
// GEMM = 8-phase counted-vmcnt template (T1+T2+T3/T4+T5):
//   256x256 tile, BK=64, 8 waves (2Mx4N), 128 KiB LDS double-buffer,
//   LDS XOR-swizzle via pre-swizzled global_load_lds source,
//   vmcnt(2) only at phases 4/8, setprio around MFMA clusters.
// Workspace ~124 MB (obuf aliases dead xb|Wqkvt region).
// ---------------------------------------------------------------------------

typedef __attribute__((ext_vector_type(8))) short bf16x8;
typedef __attribute__((ext_vector_type(4))) float f32x4;
typedef __attribute__((ext_vector_type(8))) unsigned short ushort8;

#define DEVI static __device__ __forceinline__

DEVI unsigned short f2bf(float f) {
  unsigned x = __float_as_uint(f);
  return (unsigned short)((x + 0x7fffu + ((x >> 16) & 1u)) >> 16);  // RNE
}
DEVI float bf2f(unsigned short u) { return __uint_as_float(((unsigned)u) << 16); }

DEVI void async16(const void* g, void* l) {
  __builtin_amdgcn_global_load_lds(
      (const __attribute__((address_space(1))) void*)g,
      (__attribute__((address_space(3))) void*)l, 16, 0, 0);
}

// ---------------- cast f32 -> bf16 (vectorized) ----------------------------
__global__ void k_cast_bf16(const float* __restrict__ src,
                            unsigned short* __restrict__ dst, long n) {
  long i = ((long)blockIdx.x * blockDim.x + threadIdx.x) * 4;
  const long stride = (long)gridDim.x * blockDim.x * 4;
  for (; i < n; i += stride) {
    float4 v = *(const float4*)(src + i);
    ushort4 o = make_ushort4(f2bf(v.x), f2bf(v.y), f2bf(v.z), f2bf(v.w));
    *(ushort4*)(dst + i) = o;
  }
}

// ------------- transpose + cast: src f32 [R][C] -> dst bf16 [*][R] ---------
// dst row n (= src col c0+n) is zero-filled when c0+n >= C (N-padding).
__global__ void k_transpose_cast(const float* __restrict__ src,
                                 unsigned short* __restrict__ dst,
                                 int R, int C) {
  __shared__ float tile[64][65];
  const int t = threadIdx.x;
  const int r0 = blockIdx.y * 64, c0 = blockIdx.x * 64;
#pragma unroll
  for (int i = 0; i < 16; i++) {
    int r = i * 4 + (t >> 6), c = t & 63;
    float v = 0.f;
    if (c0 + c < C) v = src[(long)(r0 + r) * C + c0 + c];
    tile[r][c] = v;
  }
  __syncthreads();
#pragma unroll
  for (int i = 0; i < 16; i++) {
    int nn = i * 4 + (t >> 6), kk = t & 63;
    dst[(long)(c0 + nn) * R + r0 + kk] = f2bf(tile[kk][nn]);
  }
}

// ---------------- concat bias [bq|bk|bv] -> [5120] -------------------------
__global__ void k_concat_bias(const float* __restrict__ bq,
                              const float* __restrict__ bk,
                              const float* __restrict__ bv,
                              float* __restrict__ dst) {
  int i = blockIdx.x * 256 + threadIdx.x;
  if (i < 5120)
    dst[i] = (i < 4096) ? bq[i] : ((i < 4608) ? bk[i - 4096] : bv[i - 4608]);
}

// ---------------- 8-phase 256^2 GEMM: C = A[M][K] * Bt[N][K]^T + bias ------
// 8 waves (2Mx4N), per-wave 128x64 output, BK=64, double-buffered 128K LDS.
// LDS XOR-swizzle: 16B slot s_phys = s_log ^ (row&7), realized by
// pre-swizzled global source (linear LDS dest for global_load_lds).
#define STG(c, half, t)                                                        \
  do {                                                                         \
    const int tt_ = ((t) < NT) ? (t) : NT - 1;                                 \
    const long ko_ = (long)tt_ * 64;                                           \
    if ((half) < 2) {                                                          \
      const unsigned short* s_ = gA + (long)(half) * 128 * Kd + ko_;           \
      unsigned short* d_ = &As_[c][(((half) * 128) + w8) * 64];                \
      async16(s_, d_);                                                         \
      async16(s_ + 64 * (long)Kd, d_ + 64 * 64);                               \
    } else {                                                                   \
      const unsigned short* s_ = gB + (long)((half) - 2) * 128 * Kd + ko_;     \
      unsigned short* d_ = &Bs_[c][((((half) - 2) * 128) + w8) * 64];          \
      async16(s_, d_);                                                         \
      async16(s_ + 64 * (long)Kd, d_ + 64 * 64);                               \
    }                                                                          \
  } while (0)

#define LOADA(c, mh)                                                           \
  do {                                                                         \
    _Pragma("unroll") for (int m4 = 0; m4 < 4; m4++) {                         \
      const unsigned short* r_ =                                               \
          &As_[c][(wr128 + ((mh)*4 + m4) * 16 + ll) * 64];                     \
      aF[m4][0] = *(const bf16x8*)(r_ + sl0 * 8);                              \
      aF[m4][1] = *(const bf16x8*)(r_ + sl1 * 8);                              \
    }                                                                          \
  } while (0)

#define LOADB(c, nh)                                                           \
  do {                                                                         \
    _Pragma("unroll") for (int n2 = 0; n2 < 2; n2++) {                         \
      const unsigned short* r_ =                                               \
          &Bs_[c][(wc64 + ((nh)*2 + n2) * 16 + ll) * 64];                      \
      bF[nh][n2][0] = *(const bf16x8*)(r_ + sl0 * 8);                          \
      bF[nh][n2][1] = *(const bf16x8*)(r_ + sl1 * 8);                          \
    }                                                                          \
  } while (0)

#define MFMAQ(mh, nh)                                                          \
  do {                                                                         \
    __builtin_amdgcn_s_setprio(1);                                             \
    _Pragma("unroll") for (int m4 = 0; m4 < 4; m4++)                           \
        _Pragma("unroll") for (int n2 = 0; n2 < 2; n2++) {                     \
      acc[(mh)*4 + m4][(nh)*2 + n2] = __builtin_amdgcn_mfma_f32_16x16x32_bf16( \
          aF[m4][0], bF[nh][n2][0], acc[(mh)*4 + m4][(nh)*2 + n2], 0, 0, 0);   \
      acc[(mh)*4 + m4][(nh)*2 + n2] = __builtin_amdgcn_mfma_f32_16x16x32_bf16( \
          aF[m4][1], bF[nh][n2][1], acc[(mh)*4 + m4][(nh)*2 + n2], 0, 0, 0);   \
    }                                                                          \
    __builtin_amdgcn_s_setprio(0);                                             \
  } while (0)

#define BAR() __builtin_amdgcn_s_barrier()
#define VM2() asm volatile("s_waitcnt vmcnt(2)" ::: "memory")

template <bool OUT_BF16, bool NMASK>
__global__ __launch_bounds__(512, 2) void k_gemm8(
    const unsigned short* __restrict__ A, const unsigned short* __restrict__ Bt,
    const float* __restrict__ bias, void* __restrict__ Cout,
    int Kd, int NN, int ldc, int Nreal) {
  __shared__ unsigned short As_[2][256 * 64];
  __shared__ unsigned short Bs_[2][256 * 64];
  const int tid = threadIdx.x;
  const int w = tid >> 6, l = tid & 63;
  const int wr = w >> 2, wc = w & 3;
  const int lg = l >> 4, ll = l & 15;
  const int w8 = w * 8;
  const int wr128 = wr * 128, wc64 = wc * 64;
  const int sl0 = lg ^ (ll & 7), sl1 = sl0 ^ 4;
  const int NT = Kd >> 6;

  // XCD-aware swizzle (gridDim.x % 8 == 0 by construction)
  const int b = blockIdx.x;
  const int cpx = gridDim.x >> 3;
  const int tile = (b & 7) * cpx + (b >> 3);
  const int tm = tile / NN, tn = tile % NN;
  const long m0 = (long)tm * 256, n0 = (long)tn * 256;

  const unsigned short* gA =
      A + (m0 + (tid >> 3)) * (long)Kd + (((tid & 7) ^ ((tid >> 3) & 7)) << 3);
  const unsigned short* gB =
      Bt + (n0 + (tid >> 3)) * (long)Kd + (((tid & 7) ^ ((tid >> 3) & 7)) << 3);

  f32x4 acc[8][4];
#pragma unroll
  for (int i = 0; i < 8; i++)
#pragma unroll
    for (int j = 0; j < 4; j++) acc[i][j] = (f32x4){0.f, 0.f, 0.f, 0.f};
  bf16x8 aF[4][2], bF[2][2][2];

  // prologue: tile0 full + tile1 half0; own-drain + barrier => all-wave t0 up
  STG(0, 0, 0); STG(0, 1, 0); STG(0, 2, 0); STG(0, 3, 0);
  STG(1, 0, 1);
  VM2();
  BAR();

  const int NITER = NT >> 1;
  for (int i = 0; i < NITER; i++) {
    const int t = 2 * i;
    // p1..p4: compute tile t (buf0); stage t+1 h1-3 (buf1), t+2 h0 (buf0)
    LOADA(0, 0); LOADB(0, 0); STG(1, 1, t + 1); BAR(); MFMAQ(0, 0); BAR();
    LOADB(0, 1);              STG(1, 2, t + 1); BAR(); MFMAQ(0, 1); BAR();
    LOADA(0, 1);              STG(1, 3, t + 1); BAR(); MFMAQ(1, 1); BAR();
    STG(0, 0, t + 2); VM2();                    BAR(); MFMAQ(1, 0); BAR();
    // p5..p8: compute tile t+1 (buf1); stage t+2 h1-3 (buf0), t+3 h0 (buf1)
    LOADA(1, 0); LOADB(1, 0); STG(0, 1, t + 2); BAR(); MFMAQ(0, 0); BAR();
    LOADB(1, 1);              STG(0, 2, t + 2); BAR(); MFMAQ(0, 1); BAR();
    LOADA(1, 1);              STG(0, 3, t + 2); BAR(); MFMAQ(1, 1); BAR();
    STG(1, 0, t + 3); VM2();                    BAR(); MFMAQ(1, 0); BAR();
  }
  if (NT & 1) {  // tail tile NT-1 in buf0 (landed: final p8's VM2+BAR)
    LOADA(0, 0); LOADB(0, 0); MFMAQ(0, 0);
    LOADB(0, 1); MFMAQ(0, 1);
    LOADA(0, 1); MFMAQ(1, 1);
    MFMAQ(1, 0);
  }

  // epilogue: C frag layout col = ll, row = lg*4 + j  [m89-verified]
#pragma unroll
  for (int nn = 0; nn < 4; nn++) {
    int col = (int)n0 + wc64 + nn * 16 + ll;
    bool ok = (!NMASK) || (col < Nreal);
    float bv_ = ok ? bias[col] : 0.f;
#pragma unroll
    for (int m = 0; m < 8; m++) {
      long row = m0 + wr128 + m * 16 + lg * 4;
#pragma unroll
      for (int j = 0; j < 4; j++) {
        float v = acc[m][nn][j] + bv_;
        if (ok) {
          if (OUT_BF16)
            ((unsigned short*)Cout)[(row + j) * (long)ldc + col] = f2bf(v);
          else
            ((float*)Cout)[(row + j) * (long)ldc + col] = v;
        }
      }
    }
  }
}

// ---------------- RoPE in place on qkv[s][0..4607] -------------------------
__global__ void k_rope(unsigned short* __restrict__ qkv,
                       const float* __restrict__ fc) {
  const int s = blockIdx.x;
  const float* f = fc + (long)s * 64;
  unsigned short* row = qkv + (long)s * 5120;
  for (int i = threadIdx.x; i < 72 * 32; i += 256) {
    int hh = i >> 5, d = i & 31;
    float c = f[d], sn = f[32 + d];
    int base = hh * 64 + d;
    float x1 = bf2f(row[base]), x2 = bf2f(row[base + 32]);
    row[base] = f2bf(x1 * c - x2 * sn);
    row[base + 32] = f2bf(x2 * c + x1 * sn);
  }
}

// ---------------- V^T: qkv v-region [s][4608+j] -> vt [j][s] ---------------
__global__ void k_transpose_v(const unsigned short* __restrict__ qkv,
                              unsigned short* __restrict__ vt) {
  __shared__ unsigned short tile[64][72];
  const int t = threadIdx.x;
  const int ts = blockIdx.x;  // 64 S-tiles
  const int tj = blockIdx.y;  // 8 col-tiles
#pragma unroll
  for (int i = 0; i < 2; i++) {
    int s = i * 32 + (t >> 3), j = (t & 7) * 8;
    *(ushort8*)&tile[s][j] =
        *(const ushort8*)(qkv + (long)(ts * 64 + s) * 5120 + 4608 + tj * 64 + j);
  }
  __syncthreads();
  int j = t >> 2, s0 = (t & 3) * 16;
  ushort8 v0, v1;
#pragma unroll
  for (int x = 0; x < 8; x++) {
    v0[x] = tile[s0 + x][j];
    v1[x] = tile[s0 + 8 + x][j];
  }
  unsigned short* dst = vt + (long)(tj * 64 + j) * 4096 + ts * 64 + s0;
  *(ushort8*)dst = v0;
  *(ushort8*)(dst + 8) = v1;
}

// ---------------- banded flash attention with sinks ------------------------
__global__ __launch_bounds__(256) void k_attn(
    const unsigned short* __restrict__ qkv, const unsigned short* __restrict__ vt,
    const float* __restrict__ sinks, unsigned short* __restrict__ o) {
  __shared__ unsigned short Ps[4][32][136];  // per-wave P, padded
  __shared__ unsigned short Ks[128][72];
  __shared__ unsigned short Vts[64][136];
  unsigned short(*Qs)[72] = (unsigned short(*)[72]) & Ps[0][0][0];  // alias

  const int n = blockIdx.x, h = blockIdx.y;
  const int kvh = h >> 3;
  const int t = threadIdx.x, w = t >> 6, l = t & 63;
  const int lg = l >> 4, ll = l & 15;

#pragma unroll
  for (int i = 0; i < 4; i++) {
    int s = 32 * i + (t >> 3), c8 = (t & 7) * 8;
    *(ushort8*)&Qs[s][c8] =
        *(const ushort8*)(qkv + (long)(n * 128 + s) * 5120 + h * 64 + c8);
  }
  __syncthreads();
  bf16x8 aq[2][2];
#pragma unroll
  for (int m = 0; m < 2; m++)
#pragma unroll
    for (int ks = 0; ks < 2; ks++)
      aq[m][ks] = *(const bf16x8*)&Qs[32 * w + 16 * m + ll][32 * ks + 8 * lg];

  f32x4 oacc[2][4];
#pragma unroll
  for (int m = 0; m < 2; m++)
#pragma unroll
    for (int nt = 0; nt < 4; nt++) oacc[m][nt] = (f32x4){0.f, 0.f, 0.f, 0.f};
  float mrun[2][4], lrun[2][4];
#pragma unroll
  for (int m = 0; m < 2; m++)
#pragma unroll
    for (int j = 0; j < 4; j++) { mrun[m][j] = -3.0e38f; lrun[m][j] = 0.f; }

  for (int ch = (n == 0 ? 1 : 0); ch < 2; ch++) {
    const int kbase = (n - 1 + ch) * 128;
#pragma unroll
    for (int i = 0; i < 4; i++) {
      int c = 32 * i + (t >> 3), c8 = (t & 7) * 8;
      *(ushort8*)&Ks[c][c8] = *(const ushort8*)(
          qkv + (long)(kbase + c) * 5120 + 4096 + kvh * 64 + c8);
    }
#pragma unroll
    for (int i = 0; i < 4; i++) {
      int d = 16 * i + (t >> 4), c8 = (t & 15) * 8;
      *(ushort8*)&Vts[d][c8] =
          *(const ushort8*)(vt + (long)(kvh * 64 + d) * 4096 + kbase + c8);
    }
    __syncthreads();

    f32x4 sacc[2][8];
#pragma unroll
    for (int m = 0; m < 2; m++)
#pragma unroll
      for (int ct = 0; ct < 8; ct++) sacc[m][ct] = (f32x4){0.f, 0.f, 0.f, 0.f};
#pragma unroll
    for (int ct = 0; ct < 8; ct++)
#pragma unroll
      for (int ks = 0; ks < 2; ks++) {
        bf16x8 bk = *(const bf16x8*)&Ks[16 * ct + ll][32 * ks + 8 * lg];
#pragma unroll
        for (int m = 0; m < 2; m++)
          sacc[m][ct] = __builtin_amdgcn_mfma_f32_16x16x32_bf16(
              aq[m][ks], bk, sacc[m][ct], 0, 0, 0);
      }

    float cmax[2][4];
#pragma unroll
    for (int m = 0; m < 2; m++)
#pragma unroll
      for (int j = 0; j < 4; j++) cmax[m][j] = -3.0e38f;
#pragma unroll
    for (int m = 0; m < 2; m++)
#pragma unroll
      for (int ct = 0; ct < 8; ct++)
#pragma unroll
        for (int j = 0; j < 4; j++) {
          int trow = 32 * w + 16 * m + 4 * lg + j;
          int cc = ch * 128 + 16 * ct + ll;
          bool valid = (cc >= trow + 1) && (cc <= trow + 128);
          float sv = valid ? sacc[m][ct][j] * 0.125f : -1.0e30f;
          sacc[m][ct][j] = sv;
          cmax[m][j] = fmaxf(cmax[m][j], sv);
        }
#pragma unroll
    for (int m = 0; m < 2; m++)
#pragma unroll
      for (int j = 0; j < 4; j++) {
        float v = cmax[m][j];
#pragma unroll
        for (int off = 1; off < 16; off <<= 1) v = fmaxf(v, __shfl_xor(v, off));
        cmax[m][j] = v;
      }

    float fsc[2][4];
#pragma unroll
    for (int m = 0; m < 2; m++)
#pragma unroll
      for (int j = 0; j < 4; j++) {
        float mnew = fmaxf(mrun[m][j], cmax[m][j]);
        fsc[m][j] = __expf(mrun[m][j] - mnew);
        mrun[m][j] = mnew;
        lrun[m][j] *= fsc[m][j];
      }

    float psum[2][4];
#pragma unroll
    for (int m = 0; m < 2; m++)
#pragma unroll
      for (int j = 0; j < 4; j++) psum[m][j] = 0.f;
#pragma unroll
    for (int m = 0; m < 2; m++)
#pragma unroll
      for (int ct = 0; ct < 8; ct++)
#pragma unroll
        for (int j = 0; j < 4; j++) {
          float p = __expf(sacc[m][ct][j] - mrun[m][j]);
          psum[m][j] += p;
          Ps[w][16 * m + 4 * lg + j][16 * ct + ll] = f2bf(p);
        }
#pragma unroll
    for (int m = 0; m < 2; m++)
#pragma unroll
      for (int j = 0; j < 4; j++) {
        float v = psum[m][j];
#pragma unroll
        for (int off = 1; off < 16; off <<= 1) v += __shfl_xor(v, off);
        lrun[m][j] += v;
#pragma unroll
        for (int nt = 0; nt < 4; nt++) oacc[m][nt][j] *= fsc[m][j];
      }

    asm volatile("s_waitcnt lgkmcnt(0)" ::: "memory");

#pragma unroll
    for (int ks = 0; ks < 4; ks++) {
      bf16x8 pa[2], vb[4];
#pragma unroll
      for (int m = 0; m < 2; m++)
        pa[m] = *(const bf16x8*)&Ps[w][16 * m + ll][32 * ks + 8 * lg];
#pragma unroll
      for (int nt = 0; nt < 4; nt++)
        vb[nt] = *(const bf16x8*)&Vts[16 * nt + ll][32 * ks + 8 * lg];
#pragma unroll
      for (int m = 0; m < 2; m++)
#pragma unroll
        for (int nt = 0; nt < 4; nt++)
          oacc[m][nt] = __builtin_amdgcn_mfma_f32_16x16x32_bf16(
              pa[m], vb[nt], oacc[m][nt], 0, 0, 0);
    }
    __syncthreads();
  }

  const float sk = sinks[h];
#pragma unroll
  for (int m = 0; m < 2; m++)
#pragma unroll
    for (int j = 0; j < 4; j++) {
      float mf = fmaxf(mrun[m][j], sk);
      float f = __expf(mrun[m][j] - mf);
      float denom = lrun[m][j] * f + __expf(sk - mf);
      float sc = f / denom;
#pragma unroll
      for (int nt = 0; nt < 4; nt++) oacc[m][nt][j] *= sc;
    }
#pragma unroll
  for (int m = 0; m < 2; m++)
#pragma unroll
    for (int nt = 0; nt < 4; nt++)
#pragma unroll
      for (int j = 0; j < 4; j++) {
        long row = (long)n * 128 + 32 * w + 16 * m + 4 * lg + j;
        int col = h * 64 + 16 * nt + ll;
        o[row * 4096 + col] = f2bf(oacc[m][nt][j]);
      }
}

// ---------------------------------------------------------------------------
extern "C" void kernel_launch(void* const* d_in, const int* in_sizes, int n_in,
                              void* d_out, int out_size, void* d_ws,
                              size_t ws_size, hipStream_t stream) {
  const float* x = (const float*)d_in[0];
  const float* fc = (const float*)d_in[1];
  const float* Wq = (const float*)d_in[2];
  const float* bq = (const float*)d_in[3];
  const float* Wk = (const float*)d_in[4];
  const float* bk = (const float*)d_in[5];
  const float* Wv = (const float*)d_in[6];
  const float* bv = (const float*)d_in[7];
  const float* Wo = (const float*)d_in[8];
  const float* bo = (const float*)d_in[9];
  const float* sinks = (const float*)d_in[10];
  float* out = (float*)d_out;

  char* p = (char*)d_ws;
  unsigned short* xb = (unsigned short*)p;     // [0, 23.6MB)
  unsigned short* obuf = (unsigned short*)p;   // alias xb|Wqkvt (both dead by attn)
  p += (size_t)4096 * 2880 * 2;
  unsigned short* Wqkvt = (unsigned short*)p;  p += (size_t)5120 * 2880 * 2;
  unsigned short* Wot = (unsigned short*)p;    p += (size_t)3072 * 4096 * 2;
  unsigned short* qkv = (unsigned short*)p;    p += (size_t)4096 * 5120 * 2;
  unsigned short* vt = (unsigned short*)p;     p += (size_t)512 * 4096 * 2;
  float* biasq = (float*)p;                    p += (size_t)5120 * 4;
  // total ~124.4 MB

  k_cast_bf16<<<2048, 256, 0, stream>>>(x, xb, (long)4096 * 2880);
  k_transpose_cast<<<dim3(64, 45), 256, 0, stream>>>(Wq, Wqkvt, 2880, 4096);
  k_transpose_cast<<<dim3(8, 45), 256, 0, stream>>>(
      Wk, Wqkvt + (size_t)4096 * 2880, 2880, 512);
  k_transpose_cast<<<dim3(8, 45), 256, 0, stream>>>(
      Wv, Wqkvt + (size_t)4608 * 2880, 2880, 512);
  k_transpose_cast<<<dim3(48, 64), 256, 0, stream>>>(Wo, Wot, 4096, 2880);
  k_concat_bias<<<20, 256, 0, stream>>>(bq, bk, bv, biasq);

  // fused QKV GEMM: [4096 x 2880] @ [2880 x 5120] -> qkv bf16 (grid 320 = 8*40)
  k_gemm8<true, false><<<16 * 20, 512, 0, stream>>>(
      xb, Wqkvt, biasq, qkv, 2880, 20, 5120, 5120);

  k_rope<<<4096, 256, 0, stream>>>(qkv, fc);
  k_transpose_v<<<dim3(64, 8), 256, 0, stream>>>(qkv, vt);

  k_attn<<<dim3(32, 64), 256, 0, stream>>>(qkv, vt, sinks, obuf);

  // output GEMM: [4096 x 4096] @ [4096 x 3072pad] -> f32 out (grid 192 = 8*24)
  k_gemm8<false, true><<<16 * 12, 512, 0, stream>>>(
      obuf, Wot, bo, out, 4096, 12, 2880, 2880);
}

// Round 6
// 584.837 us; speedup vs baseline: 1.2108x; 1.1194x over previous
//
#include <hip/hip_runtime.h>
#include <hip/hip_bf16.h>
#include <stdint.h>

// ---------------------------------------------------------------------------
// GPT-OSS sliding-window attention block, MI355X (gfx950).
// B=1 S=4096 HID=2880 HQ=64 HKV=8 D=64 W=128, sinks, RoPE.
// R3 changes vs R2 (re-submitted; R3/R4/R5 benches never acquired a GPU):
//  - GEMM: vmcnt(2) drain moved AFTER p4/p8 MFMA quadrant (adds ~620cy load
//    cover before the consumption barrier); 4x2 XCD rectangle tile map
//    (B-panel L2 sharers 1.6 -> ~3.5).
//  - Attn: band-mask tile skipping (wave-uniform): QK -44% MFMA, exp -37.5%,
//    PV -37.5%.
//  - RoPE: ushort8-vectorized.
// ---------------------------------------------------------------------------

typedef __attribute__((ext_vector_type(8))) short bf16x8;
typedef __attribute__((ext_vector_type(4))) float f32x4;
typedef __attribute__((ext_vector_type(8))) unsigned short ushort8;

#define DEVI static __device__ __forceinline__

DEVI unsigned short f2bf(float f) {
  unsigned x = __float_as_uint(f);
  return (unsigned short)((x + 0x7fffu + ((x >> 16) & 1u)) >> 16);  // RNE
}
DEVI float bf2f(unsigned short u) { return __uint_as_float(((unsigned)u) << 16); }

DEVI void async16(const void* g, void* l) {
  __builtin_amdgcn_global_load_lds(
      (const __attribute__((address_space(1))) void*)g,
      (__attribute__((address_space(3))) void*)l, 16, 0, 0);
}

// ---------------- cast f32 -> bf16 (vectorized) ----------------------------
__global__ void k_cast_bf16(const float* __restrict__ src,
                            unsigned short* __restrict__ dst, long n) {
  long i = ((long)blockIdx.x * blockDim.x + threadIdx.x) * 4;
  const long stride = (long)gridDim.x * blockDim.x * 4;
  for (; i < n; i += stride) {
    float4 v = *(const float4*)(src + i);
    ushort4 o = make_ushort4(f2bf(v.x), f2bf(v.y), f2bf(v.z), f2bf(v.w));
    *(ushort4*)(dst + i) = o;
  }
}

// ------------- transpose + cast: src f32 [R][C] -> dst bf16 [*][R] ---------
__global__ void k_transpose_cast(const float* __restrict__ src,
                                 unsigned short* __restrict__ dst,
                                 int R, int C) {
  __shared__ float tile[64][65];
  const int t = threadIdx.x;
  const int r0 = blockIdx.y * 64, c0 = blockIdx.x * 64;
#pragma unroll
  for (int i = 0; i < 16; i++) {
    int r = i * 4 + (t >> 6), c = t & 63;
    float v = 0.f;
    if (c0 + c < C) v = src[(long)(r0 + r) * C + c0 + c];
    tile[r][c] = v;
  }
  __syncthreads();
#pragma unroll
  for (int i = 0; i < 16; i++) {
    int nn = i * 4 + (t >> 6), kk = t & 63;
    dst[(long)(c0 + nn) * R + r0 + kk] = f2bf(tile[kk][nn]);
  }
}

// ---------------- concat bias [bq|bk|bv] -> [5120] -------------------------
__global__ void k_concat_bias(const float* __restrict__ bq,
                              const float* __restrict__ bk,
                              const float* __restrict__ bv,
                              float* __restrict__ dst) {
  int i = blockIdx.x * 256 + threadIdx.x;
  if (i < 5120)
    dst[i] = (i < 4096) ? bq[i] : ((i < 4608) ? bk[i - 4096] : bv[i - 4608]);
}

// ---------------- 8-phase 256^2 GEMM: C = A[M][K] * Bt[N][K]^T + bias ------
#define STG(c, half, t)                                                        \
  do {                                                                         \
    const int tt_ = ((t) < NT) ? (t) : NT - 1;                                 \
    const long ko_ = (long)tt_ * 64;                                           \
    if ((half) < 2) {                                                          \
      const unsigned short* s_ = gA + (long)(half) * 128 * Kd + ko_;           \
      unsigned short* d_ = &As_[c][(((half) * 128) + w8) * 64];                \
      async16(s_, d_);                                                         \
      async16(s_ + 64 * (long)Kd, d_ + 64 * 64);                               \
    } else {                                                                   \
      const unsigned short* s_ = gB + (long)((half) - 2) * 128 * Kd + ko_;     \
      unsigned short* d_ = &Bs_[c][((((half) - 2) * 128) + w8) * 64];          \
      async16(s_, d_);                                                         \
      async16(s_ + 64 * (long)Kd, d_ + 64 * 64);                               \
    }                                                                          \
  } while (0)

#define LOADA(c, mh)                                                           \
  do {                                                                         \
    _Pragma("unroll") for (int m4 = 0; m4 < 4; m4++) {                         \
      const unsigned short* r_ =                                               \
          &As_[c][(wr128 + ((mh)*4 + m4) * 16 + ll) * 64];                     \
      aF[m4][0] = *(const bf16x8*)(r_ + sl0 * 8);                              \
      aF[m4][1] = *(const bf16x8*)(r_ + sl1 * 8);                              \
    }                                                                          \
  } while (0)

#define LOADB(c, nh)                                                           \
  do {                                                                         \
    _Pragma("unroll") for (int n2 = 0; n2 < 2; n2++) {                         \
      const unsigned short* r_ =                                               \
          &Bs_[c][(wc64 + ((nh)*2 + n2) * 16 + ll) * 64];                      \
      bF[nh][n2][0] = *(const bf16x8*)(r_ + sl0 * 8);                          \
      bF[nh][n2][1] = *(const bf16x8*)(r_ + sl1 * 8);                          \
    }                                                                          \
  } while (0)

#define MFMAQ(mh, nh)                                                          \
  do {                                                                         \
    __builtin_amdgcn_s_setprio(1);                                             \
    _Pragma("unroll") for (int m4 = 0; m4 < 4; m4++)                           \
        _Pragma("unroll") for (int n2 = 0; n2 < 2; n2++) {                     \
      acc[(mh)*4 + m4][(nh)*2 + n2] = __builtin_amdgcn_mfma_f32_16x16x32_bf16( \
          aF[m4][0], bF[nh][n2][0], acc[(mh)*4 + m4][(nh)*2 + n2], 0, 0, 0);   \
      acc[(mh)*4 + m4][(nh)*2 + n2] = __builtin_amdgcn_mfma_f32_16x16x32_bf16( \
          aF[m4][1], bF[nh][n2][1], acc[(mh)*4 + m4][(nh)*2 + n2], 0, 0, 0);   \
    }                                                                          \
    __builtin_amdgcn_s_setprio(0);                                             \
  } while (0)

#define BAR() __builtin_amdgcn_s_barrier()
#define VM2() asm volatile("s_waitcnt vmcnt(2)" ::: "memory")

template <bool OUT_BF16, bool NMASK>
__global__ __launch_bounds__(512, 2) void k_gemm8(
    const unsigned short* __restrict__ A, const unsigned short* __restrict__ Bt,
    const float* __restrict__ bias, void* __restrict__ Cout,
    int Kd, int TMX, int TNX, int ldc, int Nreal) {
  __shared__ unsigned short As_[2][256 * 64];
  __shared__ unsigned short Bs_[2][256 * 64];
  const int tid = threadIdx.x;
  const int w = tid >> 6, l = tid & 63;
  const int wr = w >> 2, wc = w & 3;
  const int lg = l >> 4, ll = l & 15;
  const int w8 = w * 8;
  const int wr128 = wr * 128, wc64 = wc * 64;
  const int sl0 = lg ^ (ll & 7), sl1 = sl0 ^ 4;
  const int NT = Kd >> 6;

  // 4x2 XCD rectangle map: XCD x owns tm in [xr*TMX, xr*TMX+TMX) x
  // tn in [xc*TNX, xc*TNX+TNX)  (grid = 8*TMX*TNX)
  const int b = blockIdx.x;
  const int x = b & 7, r = b >> 3;
  const int tm = (x >> 1) * TMX + (r % TMX);
  const int tn = (x & 1) * TNX + (r / TMX);
  const long m0 = (long)tm * 256, n0 = (long)tn * 256;

  const unsigned short* gA =
      A + (m0 + (tid >> 3)) * (long)Kd + (((tid & 7) ^ ((tid >> 3) & 7)) << 3);
  const unsigned short* gB =
      Bt + (n0 + (tid >> 3)) * (long)Kd + (((tid & 7) ^ ((tid >> 3) & 7)) << 3);

  f32x4 acc[8][4];
#pragma unroll
  for (int i = 0; i < 8; i++)
#pragma unroll
    for (int j = 0; j < 4; j++) acc[i][j] = (f32x4){0.f, 0.f, 0.f, 0.f};
  bf16x8 aF[4][2], bF[2][2][2];

  // prologue: tile0 full + tile1 half0; own-drain + barrier => all-wave t0 up
  STG(0, 0, 0); STG(0, 1, 0); STG(0, 2, 0); STG(0, 3, 0);
  STG(1, 0, 1);
  VM2();
  BAR();

  const int NITER = NT >> 1;
  for (int i = 0; i < NITER; i++) {
    const int t = 2 * i;
    // p1..p4: compute tile t (buf0); stage t+1 h1-3 (buf1), t+2 h0 (buf0)
    LOADA(0, 0); LOADB(0, 0); STG(1, 1, t + 1); BAR(); MFMAQ(0, 0); BAR();
    LOADB(0, 1);              STG(1, 2, t + 1); BAR(); MFMAQ(0, 1); BAR();
    LOADA(0, 1);              STG(1, 3, t + 1); BAR(); MFMAQ(1, 1); BAR();
    STG(0, 0, t + 2);                           BAR(); MFMAQ(1, 0); VM2(); BAR();
    // p5..p8: compute tile t+1 (buf1); stage t+2 h1-3 (buf0), t+3 h0 (buf1)
    LOADA(1, 0); LOADB(1, 0); STG(0, 1, t + 2); BAR(); MFMAQ(0, 0); BAR();
    LOADB(1, 1);              STG(0, 2, t + 2); BAR(); MFMAQ(0, 1); BAR();
    LOADA(1, 1);              STG(0, 3, t + 2); BAR(); MFMAQ(1, 1); BAR();
    STG(1, 0, t + 3);                           BAR(); MFMAQ(1, 0); VM2(); BAR();
  }
  if (NT & 1) {  // tail tile NT-1 in buf0 (staged by final iter's p4-p7)
    LOADA(0, 0); LOADB(0, 0); MFMAQ(0, 0);
    LOADB(0, 1); MFMAQ(0, 1);
    LOADA(0, 1); MFMAQ(1, 1);
    MFMAQ(1, 0);
  }

  // epilogue: C frag layout col = ll, row = lg*4 + j  [m89-verified]
#pragma unroll
  for (int nn = 0; nn < 4; nn++) {
    int col = (int)n0 + wc64 + nn * 16 + ll;
    bool ok = (!NMASK) || (col < Nreal);
    float bv_ = ok ? bias[col] : 0.f;
#pragma unroll
    for (int m = 0; m < 8; m++) {
      long row = m0 + wr128 + m * 16 + lg * 4;
#pragma unroll
      for (int j = 0; j < 4; j++) {
        float v = acc[m][nn][j] + bv_;
        if (ok) {
          if (OUT_BF16)
            ((unsigned short*)Cout)[(row + j) * (long)ldc + col] = f2bf(v);
          else
            ((float*)Cout)[(row + j) * (long)ldc + col] = v;
        }
      }
    }
  }
}

// ---------------- RoPE in place on qkv[s][0..4607], ushort8-vectorized -----
__global__ void k_rope(unsigned short* __restrict__ qkv,
                       const float* __restrict__ fc) {
  const int s = blockIdx.x;
  const float* f = fc + (long)s * 64;
  unsigned short* row = qkv + (long)s * 5120;
  const int i = threadIdx.x;  // 288 active of 320: (head hh, 8-wide d-group g)
  if (i < 288) {
    const int hh = i >> 2, g = (i & 3) * 8;
    ushort8 a = *(const ushort8*)&row[hh * 64 + g];
    ushort8 b = *(const ushort8*)&row[hh * 64 + 32 + g];
    ushort8 ra, rb;
#pragma unroll
    for (int e = 0; e < 8; e++) {
      float c = f[g + e], sn = f[32 + g + e];
      float x1 = bf2f(a[e]), x2 = bf2f(b[e]);
      ra[e] = f2bf(x1 * c - x2 * sn);
      rb[e] = f2bf(x2 * c + x1 * sn);
    }
    *(ushort8*)&row[hh * 64 + g] = ra;
    *(ushort8*)&row[hh * 64 + 32 + g] = rb;
  }
}

// ---------------- V^T: qkv v-region [s][4608+j] -> vt [j][s] ---------------
__global__ void k_transpose_v(const unsigned short* __restrict__ qkv,
                              unsigned short* __restrict__ vt) {
  __shared__ unsigned short tile[64][72];
  const int t = threadIdx.x;
  const int ts = blockIdx.x;
  const int tj = blockIdx.y;
#pragma unroll
  for (int i = 0; i < 2; i++) {
    int s = i * 32 + (t >> 3), j = (t & 7) * 8;
    *(ushort8*)&tile[s][j] =
        *(const ushort8*)(qkv + (long)(ts * 64 + s) * 5120 + 4608 + tj * 64 + j);
  }
  __syncthreads();
  int j = t >> 2, s0 = (t & 3) * 16;
  ushort8 v0, v1;
#pragma unroll
  for (int x = 0; x < 8; x++) {
    v0[x] = tile[s0 + x][j];
    v1[x] = tile[s0 + 8 + x][j];
  }
  unsigned short* dst = vt + (long)(tj * 64 + j) * 4096 + ts * 64 + s0;
  *(ushort8*)dst = v0;
  *(ushort8*)(dst + 8) = v1;
}

// ---------------- banded flash attention with sinks ------------------------
// grid (nb=32, HQ=64); block 256 (4 waves x 32 query rows).
// Band-mask tile skipping (all wave-uniform, derived from
// valid: trow+1 <= cc <= trow+128, row-tile R = 2w+m):
//   ch0: PV ks in [w,4), exp/Ps ct in [2w,8), QK iff ct >= 2w+m
//   ch1: PV ks in [0,w], exp/Ps ct in [0,2w+1], QK iff ct <= 2w+m
__global__ __launch_bounds__(256) void k_attn(
    const unsigned short* __restrict__ qkv, const unsigned short* __restrict__ vt,
    const float* __restrict__ sinks, unsigned short* __restrict__ o) {
  __shared__ unsigned short Ps[4][32][136];
  __shared__ unsigned short Ks[128][72];
  __shared__ unsigned short Vts[64][136];
  unsigned short(*Qs)[72] = (unsigned short(*)[72]) & Ps[0][0][0];  // alias

  const int n = blockIdx.x, h = blockIdx.y;
  const int kvh = h >> 3;
  const int t = threadIdx.x, w = t >> 6, l = t & 63;
  const int lg = l >> 4, ll = l & 15;
  const int w2 = 2 * w;

#pragma unroll
  for (int i = 0; i < 4; i++) {
    int s = 32 * i + (t >> 3), c8 = (t & 7) * 8;
    *(ushort8*)&Qs[s][c8] =
        *(const ushort8*)(qkv + (long)(n * 128 + s) * 5120 + h * 64 + c8);
  }
  __syncthreads();
  bf16x8 aq[2][2];
#pragma unroll
  for (int m = 0; m < 2; m++)
#pragma unroll
    for (int ks = 0; ks < 2; ks++)
      aq[m][ks] = *(const bf16x8*)&Qs[32 * w + 16 * m + ll][32 * ks + 8 * lg];

  f32x4 oacc[2][4];
#pragma unroll
  for (int m = 0; m < 2; m++)
#pragma unroll
    for (int nt = 0; nt < 4; nt++) oacc[m][nt] = (f32x4){0.f, 0.f, 0.f, 0.f};
  float mrun[2][4], lrun[2][4];
#pragma unroll
  for (int m = 0; m < 2; m++)
#pragma unroll
    for (int j = 0; j < 4; j++) { mrun[m][j] = -3.0e38f; lrun[m][j] = 0.f; }

#pragma unroll
  for (int ch = 0; ch < 2; ch++) {
    if (ch == 0 && n == 0) continue;  // block-uniform
    const int kbase = (n - 1 + ch) * 128;
#pragma unroll
    for (int i = 0; i < 4; i++) {
      int c = 32 * i + (t >> 3), c8 = (t & 7) * 8;
      *(ushort8*)&Ks[c][c8] = *(const ushort8*)(
          qkv + (long)(kbase + c) * 5120 + 4096 + kvh * 64 + c8);
    }
#pragma unroll
    for (int i = 0; i < 4; i++) {
      int d = 16 * i + (t >> 4), c8 = (t & 15) * 8;
      *(ushort8*)&Vts[d][c8] =
          *(const ushort8*)(vt + (long)(kvh * 64 + d) * 4096 + kbase + c8);
    }
    __syncthreads();

    // S = Q K^T with dead-tile skipping
    f32x4 sacc[2][8];
#pragma unroll
    for (int m = 0; m < 2; m++)
#pragma unroll
      for (int ct = 0; ct < 8; ct++) sacc[m][ct] = (f32x4){0.f, 0.f, 0.f, 0.f};
#pragma unroll
    for (int ct = 0; ct < 8; ct++) {
      const bool pvkeep = (ch == 0) ? (ct >= w2) : (ct <= w2 + 1);
      if (!pvkeep) continue;
      bf16x8 bk0 = *(const bf16x8*)&Ks[16 * ct + ll][8 * lg];
      bf16x8 bk1 = *(const bf16x8*)&Ks[16 * ct + ll][32 + 8 * lg];
#pragma unroll
      for (int m = 0; m < 2; m++) {
        const bool qkv_ok = (ch == 0) ? (ct >= w2 + m) : (ct <= w2 + m);
        if (qkv_ok) {
          sacc[m][ct] = __builtin_amdgcn_mfma_f32_16x16x32_bf16(
              aq[m][0], bk0, sacc[m][ct], 0, 0, 0);
          sacc[m][ct] = __builtin_amdgcn_mfma_f32_16x16x32_bf16(
              aq[m][1], bk1, sacc[m][ct], 0, 0, 0);
        }
      }
    }

    // mask + scale + chunk row-max (kept tiles only)
    float cmax[2][4];
#pragma unroll
    for (int m = 0; m < 2; m++)
#pragma unroll
      for (int j = 0; j < 4; j++) cmax[m][j] = -3.0e38f;
#pragma unroll
    for (int m = 0; m < 2; m++)
#pragma unroll
      for (int ct = 0; ct < 8; ct++) {
        const bool pvkeep = (ch == 0) ? (ct >= w2) : (ct <= w2 + 1);
        if (!pvkeep) continue;
#pragma unroll
        for (int j = 0; j < 4; j++) {
          int trow = 32 * w + 16 * m + 4 * lg + j;
          int cc = ch * 128 + 16 * ct + ll;
          bool valid = (cc >= trow + 1) && (cc <= trow + 128);
          float sv = valid ? sacc[m][ct][j] * 0.125f : -1.0e30f;
          sacc[m][ct][j] = sv;
          cmax[m][j] = fmaxf(cmax[m][j], sv);
        }
      }
#pragma unroll
    for (int m = 0; m < 2; m++)
#pragma unroll
      for (int j = 0; j < 4; j++) {
        float v = cmax[m][j];
#pragma unroll
        for (int off = 1; off < 16; off <<= 1) v = fmaxf(v, __shfl_xor(v, off));
        cmax[m][j] = v;
      }

    float fsc[2][4];
#pragma unroll
    for (int m = 0; m < 2; m++)
#pragma unroll
      for (int j = 0; j < 4; j++) {
        float mnew = fmaxf(mrun[m][j], cmax[m][j]);
        fsc[m][j] = __expf(mrun[m][j] - mnew);
        mrun[m][j] = mnew;
        lrun[m][j] *= fsc[m][j];
      }

    float psum[2][4];
#pragma unroll
    for (int m = 0; m < 2; m++)
#pragma unroll
      for (int j = 0; j < 4; j++) psum[m][j] = 0.f;
#pragma unroll
    for (int m = 0; m < 2; m++)
#pragma unroll
      for (int ct = 0; ct < 8; ct++) {
        const bool pvkeep = (ch == 0) ? (ct >= w2) : (ct <= w2 + 1);
        if (!pvkeep) continue;
#pragma unroll
        for (int j = 0; j < 4; j++) {
          float p = __expf(sacc[m][ct][j] - mrun[m][j]);
          psum[m][j] += p;
          Ps[w][16 * m + 4 * lg + j][16 * ct + ll] = f2bf(p);
        }
      }
#pragma unroll
    for (int m = 0; m < 2; m++)
#pragma unroll
      for (int j = 0; j < 4; j++) {
        float v = psum[m][j];
#pragma unroll
        for (int off = 1; off < 16; off <<= 1) v += __shfl_xor(v, off);
        lrun[m][j] += v;
#pragma unroll
        for (int nt = 0; nt < 4; nt++) oacc[m][nt][j] *= fsc[m][j];
      }

    asm volatile("s_waitcnt lgkmcnt(0)" ::: "memory");

    // O += P V over kept k-slices only
#pragma unroll
    for (int ks = 0; ks < 4; ks++) {
      const bool keep = (ch == 0) ? (ks >= w) : (ks <= w);
      if (!keep) continue;
      bf16x8 pa[2], vb[4];
#pragma unroll
      for (int m = 0; m < 2; m++)
        pa[m] = *(const bf16x8*)&Ps[w][16 * m + ll][32 * ks + 8 * lg];
#pragma unroll
      for (int nt = 0; nt < 4; nt++)
        vb[nt] = *(const bf16x8*)&Vts[16 * nt + ll][32 * ks + 8 * lg];
#pragma unroll
      for (int m = 0; m < 2; m++)
#pragma unroll
        for (int nt = 0; nt < 4; nt++)
          oacc[m][nt] = __builtin_amdgcn_mfma_f32_16x16x32_bf16(
              pa[m], vb[nt], oacc[m][nt], 0, 0, 0);
    }
    __syncthreads();
  }

  const float sk = sinks[h];
#pragma unroll
  for (int m = 0; m < 2; m++)
#pragma unroll
    for (int j = 0; j < 4; j++) {
      float mf = fmaxf(mrun[m][j], sk);
      float f = __expf(mrun[m][j] - mf);
      float denom = lrun[m][j] * f + __expf(sk - mf);
      float sc = f / denom;
#pragma unroll
      for (int nt = 0; nt < 4; nt++) oacc[m][nt][j] *= sc;
    }
#pragma unroll
  for (int m = 0; m < 2; m++)
#pragma unroll
    for (int nt = 0; nt < 4; nt++)
#pragma unroll
      for (int j = 0; j < 4; j++) {
        long row = (long)n * 128 + 32 * w + 16 * m + 4 * lg + j;
        int col = h * 64 + 16 * nt + ll;
        o[row * 4096 + col] = f2bf(oacc[m][nt][j]);
      }
}

// ---------------------------------------------------------------------------
extern "C" void kernel_launch(void* const* d_in, const int* in_sizes, int n_in,
                              void* d_out, int out_size, void* d_ws,
                              size_t ws_size, hipStream_t stream) {
  const float* x = (const float*)d_in[0];
  const float* fc = (const float*)d_in[1];
  const float* Wq = (const float*)d_in[2];
  const float* bq = (const float*)d_in[3];
  const float* Wk = (const float*)d_in[4];
  const float* bk = (const float*)d_in[5];
  const float* Wv = (const float*)d_in[6];
  const float* bv = (const float*)d_in[7];
  const float* Wo = (const float*)d_in[8];
  const float* bo = (const float*)d_in[9];
  const float* sinks = (const float*)d_in[10];
  float* out = (float*)d_out;

  char* p = (char*)d_ws;
  unsigned short* xb = (unsigned short*)p;     // [0, 23.6MB)
  unsigned short* obuf = (unsigned short*)p;   // alias xb|Wqkvt (dead by attn)
  p += (size_t)4096 * 2880 * 2;
  unsigned short* Wqkvt = (unsigned short*)p;  p += (size_t)5120 * 2880 * 2;
  unsigned short* Wot = (unsigned short*)p;    p += (size_t)3072 * 4096 * 2;
  unsigned short* qkv = (unsigned short*)p;    p += (size_t)4096 * 5120 * 2;
  unsigned short* vt = (unsigned short*)p;     p += (size_t)512 * 4096 * 2;
  float* biasq = (float*)p;                    p += (size_t)5120 * 4;

  k_cast_bf16<<<2048, 256, 0, stream>>>(x, xb, (long)4096 * 2880);
  k_transpose_cast<<<dim3(64, 45), 256, 0, stream>>>(Wq, Wqkvt, 2880, 4096);
  k_transpose_cast<<<dim3(8, 45), 256, 0, stream>>>(
      Wk, Wqkvt + (size_t)4096 * 2880, 2880, 512);
  k_transpose_cast<<<dim3(8, 45), 256, 0, stream>>>(
      Wv, Wqkvt + (size_t)4608 * 2880, 2880, 512);
  k_transpose_cast<<<dim3(48, 64), 256, 0, stream>>>(Wo, Wot, 4096, 2880);
  k_concat_bias<<<20, 256, 0, stream>>>(bq, bk, bv, biasq);

  // fused QKV GEMM: grid 320 = 8 XCD * (4 tm x 10 tn)
  k_gemm8<true, false><<<320, 512, 0, stream>>>(
      xb, Wqkvt, biasq, qkv, 2880, 4, 10, 5120, 5120);

  k_rope<<<4096, 320, 0, stream>>>(qkv, fc);
  k_transpose_v<<<dim3(64, 8), 256, 0, stream>>>(qkv, vt);

  k_attn<<<dim3(32, 64), 256, 0, stream>>>(qkv, vt, sinks, obuf);

  // output GEMM: grid 192 = 8 XCD * (4 tm x 6 tn)
  k_gemm8<false, true><<<192, 512, 0, stream>>>(
      obuf, Wot, bo, out, 4096, 4, 6, 2880, 2880);
}